// Round 11
// baseline (440.883 us; speedup 1.0000x reference)
//
#include <hip/hip_runtime.h>
#include <math.h>

#define NB 65536

using f32x2 = __attribute__((ext_vector_type(2))) float;
using f32x4 = __attribute__((ext_vector_type(4))) float;
using u32x4 = __attribute__((ext_vector_type(4))) unsigned;
using bf16x8 = __attribute__((ext_vector_type(8))) __bf16;

__device__ __forceinline__ unsigned pk2(float lo, float hi) {
    return (unsigned)__builtin_bit_cast(unsigned short, (__bf16)lo)
         | ((unsigned)__builtin_bit_cast(unsigned short, (__bf16)hi) << 16);
}
__device__ __forceinline__ float softplus_f(float x) {
    return fmaxf(x, 0.f) + log1pf(expf(-fabsf(x)));
}
__device__ __forceinline__ bf16x8 asbf(f32x4 x) { return __builtin_bit_cast(bf16x8, x); }

// Barrier without vmcnt drain (LDS deps via lgkmcnt; global prefetches stay in flight)
__device__ __forceinline__ void barrier_nodrain() {
    asm volatile("s_waitcnt lgkmcnt(0)" ::: "memory");
    __builtin_amdgcn_s_barrier();
    __builtin_amdgcn_sched_barrier(0);
}

// D = A*B + D. a: lane holds row (lane&15), k=(lane>>4)*8..+8; b: lane holds col (lane&15);
// D: lane l reg r = D[(l>>4)*4+r][l&15]
#define MFMA16(acc, a, b) acc = __builtin_amdgcn_mfma_f32_16x16x32_bf16(a, b, acc, 0, 0, 0)

__device__ __forceinline__ bf16x8 cvt8(f32x4 a, f32x4 b) {
    union { bf16x8 v; unsigned u[4]; } r;
    r.u[0] = pk2(a[0], a[1]); r.u[1] = pk2(a[2], a[3]);
    r.u[2] = pk2(b[0], b[1]); r.u[3] = pk2(b[2], b[3]);
    return r.v;
}

// swizzled ys (u16 [64][256], 32KB): u16 col ^= ((row&7)<<3)
__device__ __forceinline__ const bf16x8* ys_frag(const unsigned short* ys, int row, int col) {
    return (const bf16x8*)&ys[row * 256 + (col ^ ((row & 7) << 3))];
}

// chunk loads: lane l of wave w gets fragment f = w*64+l+256j  ->  B-frag for col-tile t = w+4j
template<int NJ>
__device__ __forceinline__ void ldch(f32x4* r, const f32x4* __restrict__ src, int tid) {
    #pragma unroll
    for (int j = 0; j < NJ; ++j) r[j] = src[tid + j * 256];
}
template<int NJ>
__device__ __forceinline__ void wrch(unsigned short* buf, const f32x4* r, int tid) {
    #pragma unroll
    for (int j = 0; j < NJ; ++j) *(f32x4*)&buf[(size_t)(tid + j * 256) * 8] = r[j];
}

// Column-split LayerNorm over 256 cols: bias add -> in-wave c-reduce -> cross-wave LDS
// reduce -> apply -> pair-pack store into swizzled ys.
__device__ __forceinline__ void ln_colsplit(
    f32x4 (&acc)[4][4],
    const float* __restrict__ bias0, const float* __restrict__ gam, const float* __restrict__ bet,
    unsigned int* ysu, float* pl, float* pl2, int wid, int lane)
{
    const int c = lane & 15, q = lane >> 4;
    const int tid = threadIdx.x;
    float bb[4], gg[4], tb[4];
    #pragma unroll
    for (int j = 0; j < 4; ++j) {
        int col = (wid + 4 * j) * 16 + c;
        bb[j] = bias0[col]; gg[j] = gam[col]; tb[j] = bet[col];
    }
    f32x4 sum[4], sq[4];
    #pragma unroll
    for (int rg = 0; rg < 4; ++rg) { sum[rg] = (f32x4){0.f,0.f,0.f,0.f}; sq[rg] = sum[rg]; }
    #pragma unroll
    for (int rg = 0; rg < 4; ++rg)
        #pragma unroll
        for (int j = 0; j < 4; ++j) {
            acc[rg][j] += bb[j];
            sum[rg] += acc[rg][j];
            sq[rg] += acc[rg][j] * acc[rg][j];
        }
    #pragma unroll
    for (int m = 1; m <= 8; m <<= 1)
        #pragma unroll
        for (int rg = 0; rg < 4; ++rg)
            #pragma unroll
            for (int ri = 0; ri < 4; ++ri) {
                sum[rg][ri] += __shfl_xor(sum[rg][ri], m);
                sq[rg][ri] += __shfl_xor(sq[rg][ri], m);
            }
    if (c == 0) {
        f32x2* plv = (f32x2*)pl;
        #pragma unroll
        for (int rg = 0; rg < 4; ++rg)
            #pragma unroll
            for (int ri = 0; ri < 4; ++ri) {
                int row = rg * 16 + q * 4 + ri;
                plv[row * 4 + wid] = (f32x2){sum[rg][ri], sq[rg][ri]};
            }
    }
    barrier_nodrain();
    if (tid < 64) {
        const f32x4* p4 = (const f32x4*)pl;
        f32x4 x = p4[tid * 2], y = p4[tid * 2 + 1];
        float s = x[0] + x[2] + y[0] + y[2];
        float z = x[1] + x[3] + y[1] + y[3];
        float mean = s * (1.f / 256.f);
        float var = z * (1.f / 256.f) - mean * mean;
        float rs = rsqrtf(var + 1e-5f);
        ((f32x2*)pl2)[tid] = (f32x2){rs, -mean * rs};
    }
    barrier_nodrain();
    #pragma unroll
    for (int rg = 0; rg < 4; ++rg) {
        int r0 = rg * 16 + q * 4;
        f32x4 u = *(const f32x4*)&pl2[r0 * 2];
        f32x4 w2_ = *(const f32x4*)&pl2[r0 * 2 + 4];
        float rsv[4] = {u[0], u[2], w2_[0], w2_[2]};
        float nmv[4] = {u[1], u[3], w2_[1], w2_[3]};
        const int odd = c & 1;
        #pragma unroll
        for (int j = 0; j < 4; ++j) {
            float v0 = fmaxf(fmaf(fmaf(acc[rg][j][0], rsv[0], nmv[0]), gg[j], tb[j]), 0.f);
            float v1 = fmaxf(fmaf(fmaf(acc[rg][j][1], rsv[1], nmv[1]), gg[j], tb[j]), 0.f);
            float v2 = fmaxf(fmaf(fmaf(acc[rg][j][2], rsv[2], nmv[2]), gg[j], tb[j]), 0.f);
            float v3 = fmaxf(fmaf(fmaf(acc[rg][j][3], rsv[3], nmv[3]), gg[j], tb[j]), 0.f);
            float o0 = __shfl_xor(v0, 1), o1 = __shfl_xor(v1, 1);
            float o2 = __shfl_xor(v2, 1), o3 = __shfl_xor(v3, 1);
            unsigned p0 = pk2(odd ? o0 : v0, odd ? v0 : o0);
            unsigned p1 = pk2(odd ? o1 : v1, odd ? v1 : o1);
            unsigned p2 = pk2(odd ? o2 : v2, odd ? v2 : o2);
            unsigned p3 = pk2(odd ? o3 : v3, odd ? v3 : o3);
            unsigned pa = odd ? p2 : p0;
            unsigned pb = odd ? p3 : p1;
            int ra = r0 + (odd ? 2 : 0);
            int cp = (wid + 4 * j) * 8 + (c >> 1);
            ysu[ra * 128 + (cp ^ ((ra & 7) << 2))] = pa;
            ysu[(ra + 1) * 128 + (cp ^ (((ra + 1) & 7) << 2))] = pb;
        }
    }
    barrier_nodrain();
}

// ==================== kernel 1: prep only (192 blocks) ====================
__global__ __launch_bounds__(256) void k1_prep(
    const float* __restrict__ eW1, const float* __restrict__ eW2, const float* __restrict__ eW3,
    const float* __restrict__ vW1, const float* __restrict__ vW2,
    unsigned int* __restrict__ w1img, unsigned int* __restrict__ w2img,
    unsigned int* __restrict__ vw1img, unsigned int* __restrict__ vw2img,
    unsigned int* __restrict__ w3img)
{
    int fid = blockIdx.x * 256 + threadIdx.x;
    float v[8];
    unsigned int* dst;
    if (fid < 8192) {                       // eW1 chunks: [e][2ch] of [1024 frags]
        int e = fid >> 11, ch = (fid >> 10) & 1, rr = fid & 1023;
        int t = rr >> 6, g = (rr >> 4) & 3, c = rr & 15;
        int h = t * 16 + c, k0 = ch * 32 + g * 8;
        #pragma unroll
        for (int j = 0; j < 8; ++j) {
            int k = k0 + j;
            v[j] = (k < 44) ? eW1[(e * 44 + k) * 256 + h] : 0.f;
        }
        dst = w1img + (size_t)fid * 4;
    } else if (fid < 40960) {               // eW2 chunks: [e][8ch]
        int f = fid - 8192;
        int e = f >> 13, ch = (f >> 10) & 7, rr = f & 1023;
        int t = rr >> 6, g = (rr >> 4) & 3, c = rr & 15;
        int h = t * 16 + c, k0 = ch * 32 + g * 8;
        const float* base = eW2 + (size_t)e * 65536 + h;
        #pragma unroll
        for (int j = 0; j < 8; ++j) v[j] = base[(size_t)(k0 + j) * 256];
        dst = w2img + (size_t)f * 4;
    } else if (fid < 43008) {               // vW1 chunks: [2ch]
        int f = fid - 40960;
        int ch = f >> 10, rr = f & 1023;
        int t = rr >> 6, g = (rr >> 4) & 3, c = rr & 15;
        int h = t * 16 + c, k0 = ch * 32 + g * 8;
        #pragma unroll
        for (int j = 0; j < 8; ++j) {
            int k = k0 + j;
            v[j] = (k < 44) ? vW1[k * 256 + h] : 0.f;
        }
        dst = vw1img + (size_t)f * 4;
    } else if (fid < 47104) {               // vW2 chunks: [8ch] of [512 frags]
        int f = fid - 43008;
        int ch = f >> 9, rr = f & 511;
        int t = rr >> 6, g = (rr >> 4) & 3, c = rr & 15;
        int h = t * 16 + c, k0 = ch * 32 + g * 8;
        #pragma unroll
        for (int j = 0; j < 8; ++j) v[j] = vW2[(k0 + j) * 128 + h];
        dst = vw2img + (size_t)f * 4;
    } else {                                // eW3 images: [e] of [512 frags]
        int f = fid - 47104;
        int e = f >> 9, rr = f & 511;
        int s = rr >> 6, g = (rr >> 4) & 3, o = rr & 15;
        int k0 = s * 32 + g * 8;
        #pragma unroll
        for (int j = 0; j < 8; ++j) v[j] = eW3[(size_t)e * 4096 + (k0 + j) * 16 + o];
        dst = w3img + (size_t)f * 4;
    }
    u32x4 out;
    #pragma unroll
    for (int p = 0; p < 4; ++p) out[p] = pk2(v[2 * p], v[2 * p + 1]);
    *(u32x4*)dst = out;
}

// ==================== kernel 2: experts+router (0..1023) + value (1024..2047) ====================
// LDS 44544 B -> 3 blocks/CU (if VGPR <= 170)
#define SM_YS    0        // 32768 (router s_lds/pl_r overlay here pre-loop)
#define SM_W3S   32768    // 8192
#define SM_PL    40960    // 2048
#define SM_PL2   43008    // 512
#define SM_CMB   43520    // 1024
#define SM_TOTAL 44544

__global__ __launch_bounds__(256, 3) void k2_experts_value(
    const float* __restrict__ state,
    const float* __restrict__ rW1, const float* __restrict__ rb1,
    const float* __restrict__ rW2, const float* __restrict__ rb2,
    const float* __restrict__ eb1, const float* __restrict__ eg1, const float* __restrict__ ebt1,
    const float* __restrict__ eb2, const float* __restrict__ eg2, const float* __restrict__ ebt2,
    const float* __restrict__ eb3,
    const float* __restrict__ vb1, const float* __restrict__ vg, const float* __restrict__ vbt,
    const float* __restrict__ vb2, const float* __restrict__ vW3, const float* __restrict__ vb3,
    const f32x4* __restrict__ w1v, const f32x4* __restrict__ w2v,
    const f32x4* __restrict__ vw1v, const f32x4* __restrict__ vw2v,
    const f32x4* __restrict__ w3v,
    float* __restrict__ out_alpha, float* __restrict__ out_beta, float* __restrict__ out_value,
    float* __restrict__ out_probs)
{
    __shared__ __align__(16) unsigned char smem[SM_TOTAL];
    unsigned short* ys = (unsigned short*)(smem + SM_YS);
    unsigned int* ysu = (unsigned int*)(smem + SM_YS);
    unsigned short* w3s = (unsigned short*)(smem + SM_W3S);
    float* pl  = (float*)(smem + SM_PL);
    float* pl2 = (float*)(smem + SM_PL2);
    float* cmbs = (float*)(smem + SM_CMB);

    const int tid = threadIdx.x;
    const int wid = tid >> 6;
    const int lane = tid & 63;
    const int c = lane & 15;
    const int g = lane >> 4;
    const int stripe = wid * 16;
    const bool is_expert = (blockIdx.x < 1024);
    const int brow = (is_expert ? blockIdx.x : (blockIdx.x - 1024)) * 64;

    f32x4 rA[4], rB[4];

    if (is_expert) {
        // issue W1(e0) chunk loads first; router hides their latency
        ldch<4>(rA, w1v, tid);
        ldch<4>(rB, w1v + 1024, tid);

        // ---- inline router (fp32 exact): state transposed in LDS (ys overlay) ----
        float* s_lds = (float*)(smem + SM_YS);          // [44][64] = 11264 B
        f32x4* pl_r  = (f32x4*)(smem + SM_YS + 16384);  // [4][64]  = 4096 B
        {
            int row = tid & 63, g4 = tid >> 6;
            const float* srow = state + (size_t)(brow + row) * 44;
            #pragma unroll
            for (int k4 = 0; k4 < 3; ++k4) {
                int d4 = g4 + k4 * 4;
                if (d4 < 11) {
                    f32x4 v = *(const f32x4*)(srow + d4 * 4);
                    #pragma unroll
                    for (int qq = 0; qq < 4; ++qq) s_lds[(d4 * 4 + qq) * 64 + row] = v[qq];
                }
            }
        }
        __syncthreads();
        {
            const int w32 = __builtin_amdgcn_readfirstlane(wid * 32);
            f32x4 h[8];
            #pragma unroll
            for (int j = 0; j < 8; ++j) h[j] = *(const f32x4*)&rb1[w32 + j * 4];
            for (int d = 0; d < 44; ++d) {
                float sd = s_lds[d * 64 + lane];
                #pragma unroll
                for (int j = 0; j < 8; ++j)
                    h[j] += sd * *(const f32x4*)(rW1 + d * 128 + w32 + j * 4);
            }
            f32x4 l = {0.f, 0.f, 0.f, 0.f};
            #pragma unroll
            for (int j = 0; j < 8; ++j)
                #pragma unroll
                for (int q4 = 0; q4 < 4; ++q4)
                    l += fmaxf(h[j][q4], 0.f) * *(const f32x4*)&rW2[(w32 + j * 4 + q4) * 4];
            pl_r[wid * 64 + lane] = l;
        }
        __syncthreads();
        if (wid == 0) {
            f32x4 lg = pl_r[lane] + pl_r[64 + lane] + pl_r[128 + lane] + pl_r[192 + lane];
            lg += *(const f32x4*)rb2;
            float l0 = lg[0], l1 = lg[1], l2 = lg[2], l3 = lg[3];
            float mx = fmaxf(fmaxf(l0, l1), fmaxf(l2, l3));
            float e0 = expf(l0 - mx), e1 = expf(l1 - mx), e2 = expf(l2 - mx), e3 = expf(l3 - mx);
            float inv = 1.f / (e0 + e1 + e2 + e3);
            float p0 = e0 * inv, p1 = e1 * inv, p2 = e2 * inv, p3 = e3 * inv;
            f32x4 probs = {p0, p1, p2, p3};
            *(f32x4*)&out_probs[(size_t)(brow + lane) * 4] = probs;
            int i1 = 0; float v1 = p0;
            if (p1 > v1) { v1 = p1; i1 = 1; }
            if (p2 > v1) { v1 = p2; i1 = 2; }
            if (p3 > v1) { v1 = p3; i1 = 3; }
            int i2 = -1; float v2 = -1.f;
            if (i1 != 0 && p0 > v2) { v2 = p0; i2 = 0; }
            if (i1 != 1 && p1 > v2) { v2 = p1; i2 = 1; }
            if (i1 != 2 && p2 > v2) { v2 = p2; i2 = 2; }
            if (i1 != 3 && p3 > v2) { v2 = p3; i2 = 3; }
            float cn = 1.f / (v1 + v2 + 1e-8f);
            float c1 = v1 * cn, c2 = v2 * cn;
            f32x4 cm;
            cm[0] = (i1 == 0) ? c1 : (i2 == 0) ? c2 : 0.f;
            cm[1] = (i1 == 1) ? c1 : (i2 == 1) ? c2 : 0.f;
            cm[2] = (i1 == 2) ? c1 : (i2 == 2) ? c2 : 0.f;
            cm[3] = (i1 == 3) ? c1 : (i2 == 3) ? c2 : 0.f;
            *(f32x4*)&cmbs[lane * 4] = cm;
        }

        float mix0 = 0.f, mix1 = 0.f, mix2 = 0.f, mix3 = 0.f;

        for (int e = 0; e < 4; ++e) {
            const int en = (e < 3) ? e + 1 : 3;
            // state A-frags (reloaded per expert; L2-hot)
            bf16x8 a1s[4][2];
            #pragma unroll
            for (int rg = 0; rg < 4; ++rg) {
                const float* srow = state + (size_t)(brow + rg * 16 + c) * 44;
                f32x4 v0 = *(const f32x4*)(srow + g * 8);
                f32x4 v1 = *(const f32x4*)(srow + g * 8 + 4);
                a1s[rg][0] = cvt8(v0, v1);
                f32x4 z = {0.f,0.f,0.f,0.f}, w0 = z, w1 = z;
                if (g == 0) { w0 = *(const f32x4*)(srow + 32); w1 = *(const f32x4*)(srow + 36); }
                else if (g == 1) { w0 = *(const f32x4*)(srow + 40); }
                a1s[rg][1] = cvt8(w0, w1);
            }
            barrier_nodrain();   // ys safe to rewrite (router / prev L3 readers done)

            // ---- L1: B in registers (rA=W1ch0, rB=W1ch1) ----
            f32x4 acc[4][4];
            #pragma unroll
            for (int rg = 0; rg < 4; ++rg)
                #pragma unroll
                for (int j = 0; j < 4; ++j) acc[rg][j] = (f32x4){0.f,0.f,0.f,0.f};
            #pragma unroll
            for (int rg = 0; rg < 4; ++rg)
                #pragma unroll
                for (int j = 0; j < 4; ++j) MFMA16(acc[rg][j], a1s[rg][0], asbf(rA[j]));
            #pragma unroll
            for (int rg = 0; rg < 4; ++rg)
                #pragma unroll
                for (int j = 0; j < 4; ++j) MFMA16(acc[rg][j], a1s[rg][1], asbf(rB[j]));
            ldch<4>(rA, w2v + (size_t)(e * 8 + 0) * 1024, tid);

            ln_colsplit(acc, eb1 + e * 256, eg1 + e * 256, ebt1 + e * 256, ysu, pl, pl2, wid, lane);
            ldch<4>(rB, w2v + (size_t)(e * 8 + 1) * 1024, tid);

            // ---- W2: 8 chunks, barrier-free, B in registers ----
            #pragma unroll
            for (int rg = 0; rg < 4; ++rg)
                #pragma unroll
                for (int j = 0; j < 4; ++j) acc[rg][j] = (f32x4){0.f,0.f,0.f,0.f};
            #pragma unroll
            for (int ch = 0; ch < 8; ch += 2) {
                bf16x8 aA[4];
                #pragma unroll
                for (int rg = 0; rg < 4; ++rg) aA[rg] = *ys_frag(ys, rg * 16 + c, ch * 32 + g * 8);
                #pragma unroll
                for (int rg = 0; rg < 4; ++rg)
                    #pragma unroll
                    for (int j = 0; j < 4; ++j) MFMA16(acc[rg][j], aA[rg], asbf(rA[j]));
                if (ch < 6) ldch<4>(rA, w2v + (size_t)(e * 8 + ch + 2) * 1024, tid);
                else        ldch<2>(rA, w3v + (size_t)e * 512, tid);
                bf16x8 aB[4];
                #pragma unroll
                for (int rg = 0; rg < 4; ++rg) aB[rg] = *ys_frag(ys, rg * 16 + c, (ch + 1) * 32 + g * 8);
                #pragma unroll
                for (int rg = 0; rg < 4; ++rg)
                    #pragma unroll
                    for (int j = 0; j < 4; ++j) MFMA16(acc[rg][j], aB[rg], asbf(rB[j]));
                if (ch < 6) ldch<4>(rB, w2v + (size_t)(e * 8 + ch + 3) * 1024, tid);
            }

            ln_colsplit(acc, eb2 + e * 256, eg2 + e * 256, ebt2 + e * 256, ysu, pl, pl2, wid, lane);
            wrch<2>(w3s, rA, tid);      // stage W3 (rA holds w3 image halves)
            barrier_nodrain();          // w3s visible

            // ---- L3 (row-stripe) ----
            f32x4 acc3 = (f32x4){0.f,0.f,0.f,0.f};
            #pragma unroll
            for (int s = 0; s < 8; ++s) {
                bf16x8 a = *ys_frag(ys, stripe + c, s * 32 + g * 8);
                bf16x8 b = *(const bf16x8*)&w3s[s * 512 + g * 128 + c * 8];
                MFMA16(acc3, a, b);
            }
            float bb3 = eb3[e * 16 + c];
            mix0 += cmbs[(stripe + g * 4 + 0) * 4 + e] * (acc3[0] + bb3);
            mix1 += cmbs[(stripe + g * 4 + 1) * 4 + e] * (acc3[1] + bb3);
            mix2 += cmbs[(stripe + g * 4 + 2) * 4 + e] * (acc3[2] + bb3);
            mix3 += cmbs[(stripe + g * 4 + 3) * 4 + e] * (acc3[3] + bb3);

            ldch<4>(rA, w1v + (size_t)(en * 2) * 1024, tid);
            ldch<4>(rB, w1v + (size_t)(en * 2 + 1) * 1024, tid);
        }

        int row0 = brow + stripe + g * 4;
        float sp0 = softplus_f(mix0) + 1.f;
        float sp1 = softplus_f(mix1) + 1.f;
        float sp2 = softplus_f(mix2) + 1.f;
        float sp3 = softplus_f(mix3) + 1.f;
        if (c < 8) {
            out_alpha[(size_t)(row0 + 0) * 8 + c] = sp0;
            out_alpha[(size_t)(row0 + 1) * 8 + c] = sp1;
            out_alpha[(size_t)(row0 + 2) * 8 + c] = sp2;
            out_alpha[(size_t)(row0 + 3) * 8 + c] = sp3;
        } else {
            out_beta[(size_t)(row0 + 0) * 8 + (c - 8)] = sp0;
            out_beta[(size_t)(row0 + 1) * 8 + (c - 8)] = sp1;
            out_beta[(size_t)(row0 + 2) * 8 + (c - 8)] = sp2;
            out_beta[(size_t)(row0 + 3) * 8 + (c - 8)] = sp3;
        }
    } else {
        // ==================== value head (col-split) ====================
        ldch<4>(rA, vw1v, tid);
        ldch<4>(rB, vw1v + 1024, tid);
        bf16x8 a1s[4][2];
        #pragma unroll
        for (int rg = 0; rg < 4; ++rg) {
            const float* srow = state + (size_t)(brow + rg * 16 + c) * 44;
            f32x4 v0 = *(const f32x4*)(srow + g * 8);
            f32x4 v1 = *(const f32x4*)(srow + g * 8 + 4);
            a1s[rg][0] = cvt8(v0, v1);
            f32x4 z = {0.f,0.f,0.f,0.f}, w0 = z, w1 = z;
            if (g == 0) { w0 = *(const f32x4*)(srow + 32); w1 = *(const f32x4*)(srow + 36); }
            else if (g == 1) { w0 = *(const f32x4*)(srow + 40); }
            a1s[rg][1] = cvt8(w0, w1);
        }
        f32x4 acc[4][4];
        #pragma unroll
        for (int rg = 0; rg < 4; ++rg)
            #pragma unroll
            for (int j = 0; j < 4; ++j) acc[rg][j] = (f32x4){0.f,0.f,0.f,0.f};
        #pragma unroll
        for (int rg = 0; rg < 4; ++rg)
            #pragma unroll
            for (int j = 0; j < 4; ++j) MFMA16(acc[rg][j], a1s[rg][0], asbf(rA[j]));
        #pragma unroll
        for (int rg = 0; rg < 4; ++rg)
            #pragma unroll
            for (int j = 0; j < 4; ++j) MFMA16(acc[rg][j], a1s[rg][1], asbf(rB[j]));
        ldch<2>(rA, vw2v, tid);
        ldch<2>(rB, vw2v + 512, tid);

        ln_colsplit(acc, vb1, vg, vbt, ysu, pl, pl2, wid, lane);

        // L2: 128 cols col-split (t = wid + 4*j, j 0..1)
        f32x4 acc2[4][2];
        #pragma unroll
        for (int rg = 0; rg < 4; ++rg)
            #pragma unroll
            for (int j = 0; j < 2; ++j) acc2[rg][j] = (f32x4){0.f,0.f,0.f,0.f};
        #pragma unroll
        for (int ch = 0; ch < 8; ch += 2) {
            bf16x8 aA[4];
            #pragma unroll
            for (int rg = 0; rg < 4; ++rg) aA[rg] = *ys_frag(ys, rg * 16 + c, ch * 32 + g * 8);
            #pragma unroll
            for (int rg = 0; rg < 4; ++rg)
                #pragma unroll
                for (int j = 0; j < 2; ++j) MFMA16(acc2[rg][j], aA[rg], asbf(rA[j]));
            if (ch < 6) ldch<2>(rA, vw2v + (size_t)(ch + 2) * 512, tid);
            bf16x8 aB[4];
            #pragma unroll
            for (int rg = 0; rg < 4; ++rg) aB[rg] = *ys_frag(ys, rg * 16 + c, (ch + 1) * 32 + g * 8);
            #pragma unroll
            for (int rg = 0; rg < 4; ++rg)
                #pragma unroll
                for (int j = 0; j < 2; ++j) MFMA16(acc2[rg][j], aB[rg], asbf(rB[j]));
            if (ch < 6) ldch<2>(rB, vw2v + (size_t)(ch + 3) * 512, tid);
        }

        // L3: value = relu(y2) . vW3 + vb3 (in-register, cross-wave reduce)
        float vb2c[2], vw3c[2];
        #pragma unroll
        for (int j = 0; j < 2; ++j) {
            int col = (wid + 4 * j) * 16 + c;
            vb2c[j] = vb2[col]; vw3c[j] = vW3[col];
        }
        f32x4 part[4];
        #pragma unroll
        for (int rg = 0; rg < 4; ++rg) {
            part[rg] = (f32x4){0.f,0.f,0.f,0.f};
            #pragma unroll
            for (int j = 0; j < 2; ++j)
                #pragma unroll
                for (int ri = 0; ri < 4; ++ri)
                    part[rg][ri] += fmaxf(acc2[rg][j][ri] + vb2c[j], 0.f) * vw3c[j];
        }
        #pragma unroll
        for (int m = 1; m <= 8; m <<= 1)
            #pragma unroll
            for (int rg = 0; rg < 4; ++rg)
                #pragma unroll
                for (int ri = 0; ri < 4; ++ri)
                    part[rg][ri] += __shfl_xor(part[rg][ri], m);
        const int q = g;
        if (c == 0) {
            #pragma unroll
            for (int rg = 0; rg < 4; ++rg)
                #pragma unroll
                for (int ri = 0; ri < 4; ++ri)
                    pl[(rg * 16 + q * 4 + ri) * 4 + wid] = part[rg][ri];
        }
        barrier_nodrain();
        if (tid < 64) {
            f32x4 p = *(const f32x4*)&pl[tid * 4];
            out_value[brow + tid] = p[0] + p[1] + p[2] + p[3] + vb3[0];
        }
    }
}

// -------------------- launch --------------------
extern "C" void kernel_launch(void* const* d_in, const int* in_sizes, int n_in,
                              void* d_out, int out_size, void* d_ws, size_t ws_size,
                              hipStream_t stream)
{
    const float* state = (const float*)d_in[0];
    const float* rW1  = (const float*)d_in[1];
    const float* rb1  = (const float*)d_in[2];
    const float* rW2  = (const float*)d_in[3];
    const float* rb2  = (const float*)d_in[4];
    const float* eW1  = (const float*)d_in[5];
    const float* eb1  = (const float*)d_in[6];
    const float* eg1  = (const float*)d_in[7];
    const float* ebt1 = (const float*)d_in[8];
    const float* eW2  = (const float*)d_in[9];
    const float* eb2  = (const float*)d_in[10];
    const float* eg2  = (const float*)d_in[11];
    const float* ebt2 = (const float*)d_in[12];
    const float* eW3  = (const float*)d_in[13];
    const float* eb3  = (const float*)d_in[14];
    const float* vW1  = (const float*)d_in[15];
    const float* vb1  = (const float*)d_in[16];
    const float* vg   = (const float*)d_in[17];
    const float* vbt  = (const float*)d_in[18];
    const float* vW2  = (const float*)d_in[19];
    const float* vb2  = (const float*)d_in[20];
    const float* vW3  = (const float*)d_in[21];
    const float* vb3  = (const float*)d_in[22];

    float* out = (float*)d_out;
    float* out_alpha = out;
    float* out_beta  = out + (size_t)NB * 8;
    float* out_value = out + (size_t)NB * 16;
    float* out_probs = out + (size_t)NB * 17;

    char* ws = (char*)d_ws;
    unsigned int* w1img   = (unsigned int*)(ws + 0x00000);   // 128 KB: 8 chunks of 16KB
    unsigned int* w2img   = (unsigned int*)(ws + 0x20000);   // 512 KB: 32 chunks
    unsigned int* vw1img  = (unsigned int*)(ws + 0xA0000);   // 32 KB : 2 chunks
    unsigned int* vw2img  = (unsigned int*)(ws + 0xA8000);   // 64 KB : 8 half-chunks
    unsigned int* w3img   = (unsigned int*)(ws + 0xB8000);   // 32 KB : 4 half-chunks

    hipLaunchKernelGGL(k1_prep, dim3(192), dim3(256), 0, stream,
                       eW1, eW2, eW3, vW1, vW2,
                       w1img, w2img, vw1img, vw2img, w3img);
    hipLaunchKernelGGL(k2_experts_value, dim3(2048), dim3(256), 0, stream,
                       state, rW1, rb1, rW2, rb2,
                       eb1, eg1, ebt1, eb2, eg2, ebt2, eb3,
                       vb1, vg, vbt, vb2, vW3, vb3,
                       (const f32x4*)w1img, (const f32x4*)w2img,
                       (const f32x4*)vw1img, (const f32x4*)vw2img,
                       (const f32x4*)w3img,
                       out_alpha, out_beta, out_value, out_probs);
}